// Round 1
// baseline (5287.827 us; speedup 1.0000x reference)
//
#include <hip/hip_runtime.h>

#define HWN 16384
#define WDIM 128

// ---------- K1/K5: C[M,16384] = A[M,K] * B[K,16384] fp32, per-batch z ----------
__global__ __launch_bounds__(256) void gemm128_f32(
    const float* __restrict__ A, const float* __restrict__ B, float* __restrict__ C,
    int M, int K, long sA, long sB, long sC) {
  __shared__ float As[8][128];
  __shared__ float Bs[8][128];
  const int bz = blockIdx.z;
  A += (long)bz * sA;
  B += (long)bz * sB;
  C += (long)bz * sC;
  const int tid = threadIdx.x;
  const int tn = tid & 15, tm = tid >> 4;
  const int n0 = blockIdx.x << 7, m0 = blockIdx.y << 7;
  const int lar = tid >> 1, lac = (tid & 1) << 2;      // A tile: 128 rows x 8 k
  const int lbr = tid >> 5, lbc = (tid & 31) << 2;     // B tile: 8 k x 128 cols
  float acc[8][8] = {};
  for (int k0 = 0; k0 < K; k0 += 8) {
    float4 av = *(const float4*)(A + (long)(m0 + lar) * K + (k0 + lac));
    float4 bv = *(const float4*)(B + (long)(k0 + lbr) * HWN + (n0 + lbc));
    As[lac + 0][lar] = av.x;
    As[lac + 1][lar] = av.y;
    As[lac + 2][lar] = av.z;
    As[lac + 3][lar] = av.w;
    *(float4*)&Bs[lbr][lbc] = bv;
    __syncthreads();
#pragma unroll
    for (int kk = 0; kk < 8; ++kk) {
      float a[8], b[8];
#pragma unroll
      for (int i = 0; i < 8; ++i) a[i] = As[kk][(tm << 3) + i];
#pragma unroll
      for (int j = 0; j < 8; ++j) b[j] = Bs[kk][(tn << 3) + j];
#pragma unroll
      for (int i = 0; i < 8; ++i)
#pragma unroll
        for (int j = 0; j < 8; ++j) acc[i][j] += a[i] * b[j];
    }
    __syncthreads();
  }
#pragma unroll
  for (int i = 0; i < 8; ++i) {
    long row = (long)(m0 + (tm << 3) + i) * HWN + n0 + (tn << 3);
    *(float4*)(C + row) = make_float4(acc[i][0], acc[i][1], acc[i][2], acc[i][3]);
    *(float4*)(C + row + 4) = make_float4(acc[i][4], acc[i][5], acc[i][6], acc[i][7]);
  }
}

// ---------- K2a: depthwise 3x3 on q,k for one head + Gram/sumsq partials ----------
__global__ __launch_bounds__(256) void dwqk_gram(
    const float* __restrict__ q1, const float* __restrict__ dww,
    float* __restrict__ gram, float* __restrict__ qs, float* __restrict__ ks, int b0) {
  __shared__ float qk[128 * 97];  // [pixel][c2], c2: 0..47 q, 48..95 k, stride 97
  const int tid = threadIdx.x;
  const int bz = blockIdx.z >> 3;  // chunk-local batch
  const int h = blockIdx.z & 7;
  const int b = b0 + bz;
  const int px = tid & 127;
  const int half = tid >> 7;  // 0: q channels, 1: k channels
  const int X = (blockIdx.x << 4) + (px & 15);
  const int Y = (blockIdx.y << 3) + (px >> 4);
  const int chbase = h * 48 + (half ? 384 : 0);
  const float* src0 = q1 + ((long)bz * 1152 + chbase) * HWN;
  for (int c = 0; c < 48; ++c) {
    const float* wp = dww + (long)(chbase + c) * 9;
    const float* sp = src0 + (long)c * HWN;
    float acc = 0.f;
#pragma unroll
    for (int dy = 0; dy < 3; ++dy) {
      int yy = Y + dy - 1;
      if (yy >= 0 && yy < WDIM) {
#pragma unroll
        for (int dx = 0; dx < 3; ++dx) {
          int xx = X + dx - 1;
          if (xx >= 0 && xx < WDIM) acc += wp[dy * 3 + dx] * sp[yy * WDIM + xx];
        }
      }
    }
    qk[px * 97 + half * 48 + c] = acc;
  }
  __syncthreads();
  // Gram partial: 48x48 = 16x16 threads * 3x3 micro
  const int c0 = (tid & 15) * 3, d0 = (tid >> 4) * 3;
  float g[3][3] = {};
  for (int p = 0; p < 128; ++p) {
    const float* row = qk + p * 97;
    float a0 = row[c0], a1 = row[c0 + 1], a2 = row[c0 + 2];
    float e0 = row[48 + d0], e1 = row[48 + d0 + 1], e2 = row[48 + d0 + 2];
    g[0][0] += a0 * e0; g[0][1] += a0 * e1; g[0][2] += a0 * e2;
    g[1][0] += a1 * e0; g[1][1] += a1 * e1; g[1][2] += a1 * e2;
    g[2][0] += a2 * e0; g[2][1] += a2 * e1; g[2][2] += a2 * e2;
  }
  float* gb = gram + (long)(b * 8 + h) * 2304;
#pragma unroll
  for (int i = 0; i < 3; ++i)
#pragma unroll
    for (int j = 0; j < 3; ++j) atomicAdd(gb + (c0 + i) * 48 + d0 + j, g[i][j]);
  // sum of squares for l2norm
  if (tid < 96) {
    float s = 0.f;
    for (int p = 0; p < 128; ++p) {
      float v = qk[p * 97 + tid];
      s += v * v;
    }
    if (tid < 48)
      atomicAdd(qs + b * 384 + h * 48 + tid, s);
    else
      atomicAdd(ks + b * 384 + h * 48 + (tid - 48), s);
  }
}

// ---------- K2b: depthwise 3x3 on v -> vbuf ----------
__global__ __launch_bounds__(256) void dwv(
    const float* __restrict__ q1, const float* __restrict__ dww, float* __restrict__ vbuf) {
  const int tid = threadIdx.x;
  const int bz = blockIdx.z;
  const int X = (blockIdx.x << 6) + (tid & 63);
  const int Y = (blockIdx.y << 2) + (tid >> 6);
  for (int c = 0; c < 384; ++c) {
    int ch = 768 + c;
    const float* wp = dww + (long)ch * 9;
    const float* sp = q1 + ((long)bz * 1152 + ch) * HWN;
    float acc = 0.f;
#pragma unroll
    for (int dy = 0; dy < 3; ++dy) {
      int yy = Y + dy - 1;
      if (yy >= 0 && yy < WDIM) {
#pragma unroll
        for (int dx = 0; dx < 3; ++dx) {
          int xx = X + dx - 1;
          if (xx >= 0 && xx < WDIM) acc += wp[dy * 3 + dx] * sp[yy * WDIM + xx];
        }
      }
    }
    vbuf[((long)bz * 384 + c) * HWN + Y * WDIM + X] = acc;
  }
}

// ---------- K3: normalize Gram, top-7, masked softmax -> attn ----------
__global__ __launch_bounds__(64) void topk_softmax(
    const float* __restrict__ gram, const float* __restrict__ qs, const float* __restrict__ ks,
    const float* __restrict__ temp, float* __restrict__ attn, int b0) {
  const int z = blockIdx.x;
  const int b = b0 + (z >> 3), h = z & 7;
  __shared__ float kn[48];
  const int tid = threadIdx.x;
  if (tid < 48) kn[tid] = fmaxf(sqrtf(ks[b * 384 + h * 48 + tid]), 1e-12f);
  __syncthreads();
  if (tid >= 48) return;
  const int c = tid;
  float qn = fmaxf(sqrtf(qs[b * 384 + h * 48 + c]), 1e-12f);
  float tv = temp[h];
  const float* gr = gram + (long)(b * 8 + h) * 2304 + c * 48;
  float s[48];
#pragma unroll
  for (int d = 0; d < 48; ++d) s[d] = gr[d] / (qn * kn[d]) * tv;
  unsigned long long sel = 0ull;
  float m0 = 0.f;
  for (int it = 0; it < 7; ++it) {
    float mx = -3.0e38f;
    int mi = 0;
#pragma unroll
    for (int d = 0; d < 48; ++d) {
      bool taken = (sel >> d) & 1ull;
      if (!taken && s[d] > mx) { mx = s[d]; mi = d; }  // strict > : first-index ties like lax.top_k
    }
    sel |= (1ull << mi);
    if (it == 0) m0 = mx;
  }
  float sum = 0.f;
  float e[48];
#pragma unroll
  for (int d = 0; d < 48; ++d) {
    bool t = (sel >> d) & 1ull;
    float ev = t ? expf(s[d] - m0) : 0.f;
    e[d] = ev;
    sum += ev;
  }
  float inv = 1.f / sum;
  float* ar = attn + (long)(b * 8 + h) * 2304 + c * 48;
#pragma unroll
  for (int d = 0; d < 48; ++d) ar[d] = e[d] * inv;
}

// ---------- K4: M_b = proj_w @ blockdiag(attn_b), per (b,h) block-column ----------
__global__ __launch_bounds__(256) void build_M(
    const float* __restrict__ attn, const float* __restrict__ pw, float* __restrict__ Mm, int b0) {
  const int b = b0 + blockIdx.x;
  const int h = blockIdx.y;
  __shared__ float at[48][49];
  const int tid = threadIdx.x;
  for (int i = tid; i < 2304; i += 256) at[i / 48][i % 48] = attn[(long)(b * 8 + h) * 2304 + i];
  __syncthreads();
  for (int idx = tid; idx < 384 * 48; idx += 256) {
    int o = idx / 48, d = idx % 48;
    const float* pr = pw + (long)o * 384 + h * 48;
    float acc = 0.f;
#pragma unroll
    for (int c = 0; c < 48; ++c) acc += pr[c] * at[c][d];
    Mm[((long)b * 384 + o) * 384 + h * 48 + d] = acc;
  }
}

extern "C" void kernel_launch(void* const* d_in, const int* in_sizes, int n_in,
                              void* d_out, int out_size, void* d_ws, size_t ws_size,
                              hipStream_t stream) {
  const float* x = (const float*)d_in[0];       // (8,384,128,128)
  const float* qkv_w = (const float*)d_in[1];   // (1152,384)
  const float* dw_w = (const float*)d_in[2];    // (1152,1,3,3)
  const float* proj_w = (const float*)d_in[3];  // (384,384)
  const float* temp = (const float*)d_in[4];    // (8,)
  float* out = (float*)d_out;
  float* ws = (float*)d_ws;

  // ws layout (floats)
  float* gram = ws;                 // 8*8*48*48 = 147456
  float* qs = gram + 147456;        // 8*384
  float* ks = qs + 3072;            // 8*384
  float* attn = ks + 3072;          // 147456
  float* Mm = attn + 147456;        // 8*384*384 = 1179648
  float* qkv1 = Mm + 1179648;       // nb*1152*16384
  const long SMALLS = 1480704L;
  const long PERB = 25165824L;      // 1152*16384 + 384*16384
  long wsf = (long)(ws_size / 4);
  int nb = (int)((wsf - SMALLS) / PERB);
  if (nb < 1) nb = 1;
  if (nb > 8) nb = 8;
  float* vbuf = qkv1 + (long)nb * 18874368L;

  hipMemsetAsync(gram, 0, (147456 + 3072 + 3072) * sizeof(float), stream);

  for (int b0 = 0; b0 < 8; b0 += nb) {
    int nbc = (8 - b0 < nb) ? (8 - b0) : nb;
    // K1: qkv1 = qkv_w @ x[b]   (M=1152, K=384)
    gemm128_f32<<<dim3(128, 9, nbc), 256, 0, stream>>>(
        qkv_w, x + (long)b0 * 6291456L, qkv1, 1152, 384, 0L, 6291456L, 18874368L);
    // K2a: dw on q,k + Gram/sumsq partials
    dwqk_gram<<<dim3(8, 16, nbc * 8), 256, 0, stream>>>(qkv1, dw_w, gram, qs, ks, b0);
    // K2b: dw on v -> vbuf
    dwv<<<dim3(2, 32, nbc), 256, 0, stream>>>(qkv1, dw_w, vbuf);
    // K3: attn
    topk_softmax<<<dim3(nbc * 8), 64, 0, stream>>>(gram, qs, ks, temp, attn, b0);
    // K4: M_b
    build_M<<<dim3(nbc, 8), 256, 0, stream>>>(attn, proj_w, Mm, b0);
    // K5: out[b] = M_b @ vbuf[b]   (M=384, K=384)
    gemm128_f32<<<dim3(128, 3, nbc), 256, 0, stream>>>(
        Mm + (long)b0 * 147456L, vbuf, out + (long)b0 * 6291456L, 384, 384, 147456L, 6291456L, 6291456L);
  }
}

// Round 2
// 2915.969 us; speedup vs baseline: 1.8134x; 1.8134x over previous
//
#include <hip/hip_runtime.h>

#define HWN 16384
#define WDIM 128

// ---------- K1/K5: C[M,16384] = A[M,K] * B[K,16384] fp32, per-batch z ----------
__global__ __launch_bounds__(256) void gemm128_f32(
    const float* __restrict__ A, const float* __restrict__ B, float* __restrict__ C,
    int M, int K, long sA, long sB, long sC) {
  __shared__ float As[8][128];
  __shared__ float Bs[8][128];
  const int bz = blockIdx.z;
  A += (long)bz * sA;
  B += (long)bz * sB;
  C += (long)bz * sC;
  const int tid = threadIdx.x;
  const int tn = tid & 15, tm = tid >> 4;
  const int n0 = blockIdx.x << 7, m0 = blockIdx.y << 7;
  const int lar = tid >> 1, lac = (tid & 1) << 2;      // A tile: 128 rows x 8 k
  const int lbr = tid >> 5, lbc = (tid & 31) << 2;     // B tile: 8 k x 128 cols
  float acc[8][8] = {};
  for (int k0 = 0; k0 < K; k0 += 8) {
    float4 av = *(const float4*)(A + (long)(m0 + lar) * K + (k0 + lac));
    float4 bv = *(const float4*)(B + (long)(k0 + lbr) * HWN + (n0 + lbc));
    As[lac + 0][lar] = av.x;
    As[lac + 1][lar] = av.y;
    As[lac + 2][lar] = av.z;
    As[lac + 3][lar] = av.w;
    *(float4*)&Bs[lbr][lbc] = bv;
    __syncthreads();
#pragma unroll
    for (int kk = 0; kk < 8; ++kk) {
      float a[8], b[8];
#pragma unroll
      for (int i = 0; i < 8; ++i) a[i] = As[kk][(tm << 3) + i];
#pragma unroll
      for (int j = 0; j < 8; ++j) b[j] = Bs[kk][(tn << 3) + j];
#pragma unroll
      for (int i = 0; i < 8; ++i)
#pragma unroll
        for (int j = 0; j < 8; ++j) acc[i][j] += a[i] * b[j];
    }
    __syncthreads();
  }
#pragma unroll
  for (int i = 0; i < 8; ++i) {
    long row = (long)(m0 + (tm << 3) + i) * HWN + n0 + (tn << 3);
    *(float4*)(C + row) = make_float4(acc[i][0], acc[i][1], acc[i][2], acc[i][3]);
    *(float4*)(C + row + 4) = make_float4(acc[i][4], acc[i][5], acc[i][6], acc[i][7]);
  }
}

// ---------- dw_all: depthwise 3x3 on ALL 1152 channels, + q/k sumsq fused ----------
// block: one (batch, channel, ytile-of-8-rows). 256 threads = 128x * 2y, 4 px/thread.
__global__ __launch_bounds__(256) void dw_all(
    const float* __restrict__ qkv1, const float* __restrict__ dww,
    float* __restrict__ dwout, float* __restrict__ qs, float* __restrict__ ks, int b0) {
  __shared__ float L[10 * 128];  // rows y0-1 .. y0+8, zero-padded at image edges
  const int tid = threadIdx.x;
  const int ytile = blockIdx.x;  // 0..15
  const int ch = blockIdx.y;     // 0..1151
  const int bz = blockIdx.z;
  const int y0 = ytile << 3;
  const float* sp = qkv1 + ((long)bz * 1152 + ch) * HWN;
#pragma unroll
  for (int i = tid; i < 1280; i += 256) {
    int r = i >> 7, cx = i & 127;
    int gy = y0 - 1 + r;
    L[i] = (gy >= 0 && gy < WDIM) ? sp[gy * WDIM + cx] : 0.f;
  }
  const float* wp = dww + (long)ch * 9;
  float w00 = wp[0], w01 = wp[1], w02 = wp[2];
  float w10 = wp[3], w11 = wp[4], w12 = wp[5];
  float w20 = wp[6], w21 = wp[7], w22 = wp[8];
  __syncthreads();
  const int x = tid & 127;
  const int ys = (tid >> 7) << 2;  // 0 or 4
  float acc[4] = {0.f, 0.f, 0.f, 0.f};
#pragma unroll
  for (int r = 0; r < 6; ++r) {
    const float* row = L + (ys + r) * 128;
    float a = (x > 0) ? row[x - 1] : 0.f;
    float m = row[x];
    float c = (x < 127) ? row[x + 1] : 0.f;
    // output px j (y = y0+ys+j) uses LDS rows j..j+2; weight row = r - j
#pragma unroll
    for (int j = 0; j < 4; ++j) {
      int wr = r - j;
      if (wr == 0) acc[j] += w00 * a + w01 * m + w02 * c;
      if (wr == 1) acc[j] += w10 * a + w11 * m + w12 * c;
      if (wr == 2) acc[j] += w20 * a + w21 * m + w22 * c;
    }
  }
  float* op = dwout + ((long)bz * 1152 + ch) * HWN + (y0 + ys) * WDIM + x;
  op[0] = acc[0];
  op[128] = acc[1];
  op[256] = acc[2];
  op[384] = acc[3];
  if (ch < 768) {
    float sq = acc[0] * acc[0] + acc[1] * acc[1] + acc[2] * acc[2] + acc[3] * acc[3];
#pragma unroll
    for (int off = 32; off >= 1; off >>= 1) sq += __shfl_down(sq, off, 64);
    if ((tid & 63) == 0) {
      int b = b0 + bz;
      if (ch < 384)
        atomicAdd(qs + b * 384 + ch, sq);
      else
        atomicAdd(ks + b * 384 + (ch - 384), sq);
    }
  }
}

// ---------- gram48: G[b,h] += Qd(48,P) * Kd(48,P)^T over a 512-px chunk ----------
// 64 threads, 6x6 micro-tile (8x8 thread grid over 48x48), pad-65 conflict-free.
__global__ __launch_bounds__(64) void gram48(
    const float* __restrict__ dwout, float* __restrict__ gram, int b0) {
  __shared__ float qt[48 * 65];
  __shared__ float kt[48 * 65];
  const int tid = threadIdx.x;
  const int kc = blockIdx.x;  // 0..31 (512 px each)
  const int h = blockIdx.y;
  const int bz = blockIdx.z;
  const float* Q = dwout + ((long)bz * 1152 + h * 48) * HWN;
  const float* K = Q + 384L * HWN;
  const int c0 = (tid & 7) * 6;
  const int d0 = (tid >> 3) * 6;
  float g[6][6] = {};
  for (int p0 = kc * 512; p0 < kc * 512 + 512; p0 += 64) {
#pragma unroll 4
    for (int c = 0; c < 48; ++c) {
      qt[c * 65 + tid] = Q[(long)c * HWN + p0 + tid];
      kt[c * 65 + tid] = K[(long)c * HWN + p0 + tid];
    }
    __syncthreads();
#pragma unroll 8
    for (int p = 0; p < 64; ++p) {
      float a[6], e[6];
#pragma unroll
      for (int i = 0; i < 6; ++i) a[i] = qt[(c0 + i) * 65 + p];
#pragma unroll
      for (int j = 0; j < 6; ++j) e[j] = kt[(d0 + j) * 65 + p];
#pragma unroll
      for (int i = 0; i < 6; ++i)
#pragma unroll
        for (int j = 0; j < 6; ++j) g[i][j] += a[i] * e[j];
    }
    __syncthreads();
  }
  float* gb = gram + (long)((b0 + bz) * 8 + h) * 2304;
#pragma unroll
  for (int i = 0; i < 6; ++i)
#pragma unroll
    for (int j = 0; j < 6; ++j) atomicAdd(gb + (c0 + i) * 48 + d0 + j, g[i][j]);
}

// ---------- K3: normalize Gram, top-7, masked softmax -> attn ----------
__global__ __launch_bounds__(64) void topk_softmax(
    const float* __restrict__ gram, const float* __restrict__ qs, const float* __restrict__ ks,
    const float* __restrict__ temp, float* __restrict__ attn, int b0) {
  const int z = blockIdx.x;
  const int b = b0 + (z >> 3), h = z & 7;
  __shared__ float kn[48];
  const int tid = threadIdx.x;
  if (tid < 48) kn[tid] = fmaxf(sqrtf(ks[b * 384 + h * 48 + tid]), 1e-12f);
  __syncthreads();
  if (tid >= 48) return;
  const int c = tid;
  float qn = fmaxf(sqrtf(qs[b * 384 + h * 48 + c]), 1e-12f);
  float tv = temp[h];
  const float* gr = gram + (long)(b * 8 + h) * 2304 + c * 48;
  float s[48];
#pragma unroll
  for (int d = 0; d < 48; ++d) s[d] = gr[d] / (qn * kn[d]) * tv;
  unsigned long long sel = 0ull;
  float m0 = 0.f;
  for (int it = 0; it < 7; ++it) {
    float mx = -3.0e38f;
    int mi = 0;
#pragma unroll
    for (int d = 0; d < 48; ++d) {
      bool taken = (sel >> d) & 1ull;
      if (!taken && s[d] > mx) { mx = s[d]; mi = d; }
    }
    sel |= (1ull << mi);
    if (it == 0) m0 = mx;
  }
  float sum = 0.f;
  float e[48];
#pragma unroll
  for (int d = 0; d < 48; ++d) {
    bool t = (sel >> d) & 1ull;
    float ev = t ? expf(s[d] - m0) : 0.f;
    e[d] = ev;
    sum += ev;
  }
  float inv = 1.f / sum;
  float* ar = attn + (long)(b * 8 + h) * 2304 + c * 48;
#pragma unroll
  for (int d = 0; d < 48; ++d) ar[d] = e[d] * inv;
}

// ---------- K4: M_b = proj_w @ blockdiag(attn_b), per (b,h) block-column ----------
__global__ __launch_bounds__(256) void build_M(
    const float* __restrict__ attn, const float* __restrict__ pw, float* __restrict__ Mm, int b0) {
  const int b = b0 + blockIdx.x;
  const int h = blockIdx.y;
  __shared__ float at[48][49];
  const int tid = threadIdx.x;
  for (int i = tid; i < 2304; i += 256) at[i / 48][i % 48] = attn[(long)(b * 8 + h) * 2304 + i];
  __syncthreads();
  for (int idx = tid; idx < 384 * 48; idx += 256) {
    int o = idx / 48, d = idx % 48;
    const float* pr = pw + (long)o * 384 + h * 48;
    float acc = 0.f;
#pragma unroll
    for (int c = 0; c < 48; ++c) acc += pr[c] * at[c][d];
    Mm[((long)b * 384 + o) * 384 + h * 48 + d] = acc;
  }
}

extern "C" void kernel_launch(void* const* d_in, const int* in_sizes, int n_in,
                              void* d_out, int out_size, void* d_ws, size_t ws_size,
                              hipStream_t stream) {
  const float* x = (const float*)d_in[0];       // (8,384,128,128)
  const float* qkv_w = (const float*)d_in[1];   // (1152,384)
  const float* dw_w = (const float*)d_in[2];    // (1152,1,3,3)
  const float* proj_w = (const float*)d_in[3];  // (384,384)
  const float* temp = (const float*)d_in[4];    // (8,)
  float* out = (float*)d_out;
  float* ws = (float*)d_ws;

  // ws layout (floats)
  float* gram = ws;                 // 8*8*48*48 = 147456
  float* qs = gram + 147456;        // 8*384
  float* ks = qs + 3072;            // 8*384
  float* attn = ks + 3072;          // 147456
  float* Mm = attn + 147456;        // 8*384*384 = 1179648
  float* qkv1 = Mm + 1179648;       // nb*1152*16384
  const long SMALLS = 1480704L;
  const long PERB = 37748736L;      // qkv1 (1152*16384) + dwout (1152*16384)
  long wsf = (long)(ws_size / 4);
  int nb = (int)((wsf - SMALLS) / PERB);
  if (nb < 1) nb = 1;
  if (nb > 8) nb = 8;
  float* dwout = qkv1 + (long)nb * 18874368L;

  hipMemsetAsync(gram, 0, (147456 + 3072 + 3072) * sizeof(float), stream);

  for (int b0 = 0; b0 < 8; b0 += nb) {
    int nbc = (8 - b0 < nb) ? (8 - b0) : nb;
    // K1: qkv1 = qkv_w @ x[b]   (M=1152, K=384)
    gemm128_f32<<<dim3(128, 9, nbc), 256, 0, stream>>>(
        qkv_w, x + (long)b0 * 6291456L, qkv1, 1152, 384, 0L, 6291456L, 18874368L);
    // dw: all 1152 channels, q/k sumsq fused
    dw_all<<<dim3(16, 1152, nbc), 256, 0, stream>>>(qkv1, dw_w, dwout, qs, ks, b0);
    // gram: G[b,h] = Qd.Kd^T
    gram48<<<dim3(32, 8, nbc), 64, 0, stream>>>(dwout, gram, b0);
    // K3: attn
    topk_softmax<<<dim3(nbc * 8), 64, 0, stream>>>(gram, qs, ks, temp, attn, b0);
    // K4: M_b
    build_M<<<dim3(nbc, 8), 256, 0, stream>>>(attn, proj_w, Mm, b0);
    // K5: out[b] = M_b @ vbuf[b]   (M=384, K=384); vbuf = dwout v-planes
    gemm128_f32<<<dim3(128, 3, nbc), 256, 0, stream>>>(
        Mm + (long)b0 * 147456L, dwout + 768L * HWN, out + (long)b0 * 6291456L,
        384, 384, 147456L, 18874368L, 6291456L);
  }
}

// Round 3
// 1662.076 us; speedup vs baseline: 3.1815x; 1.7544x over previous
//
#include <hip/hip_runtime.h>

#define HWN 16384
#define WDIM 128

typedef __bf16 bf16x8 __attribute__((ext_vector_type(8)));
typedef float floatx4 __attribute__((ext_vector_type(4)));

#define LSTR 44  // LDS row stride in bf16 (pad 32->44: staging writes & frag reads <=2-way)

// ---------- MFMA GEMM: C[M,16384] = (Ah+Al)[M,K] x split(B)[K,16384], fp32-quality ----------
// 128x128 tile, BK=32, 4 waves (2x2 quadrants of 64x64), 16x16x32 bf16 MFMA, 3 products.
__global__ __launch_bounds__(256, 2) void gemm_mfma3(
    const __bf16* __restrict__ Ah, const __bf16* __restrict__ Al,
    const float* __restrict__ B, float* __restrict__ C,
    int K, long sA, long sB, long sC) {
  __shared__ __bf16 sAh[128 * LSTR], sAl[128 * LSTR], sBh[128 * LSTR], sBl[128 * LSTR];
  const int bz = blockIdx.z;
  Ah += (long)bz * sA;
  Al += (long)bz * sA;
  B += (long)bz * sB;
  C += (long)bz * sC;
  const int tid = threadIdx.x;
  const int n0 = blockIdx.x << 7, m0 = blockIdx.y << 7;
  // staging assignments
  const int arow = tid >> 1, akq = (tid & 1) << 4;  // A: 2 threads/row, 16 k each
  const int bn = (tid & 63) << 1;                   // B: pixel pair
  const int bkb = (tid >> 6) << 3;                  // B: k-block of 8 (per wave)
  // fragment assignments
  const int lane = tid & 63, wv = tid >> 6;
  const int mq = (wv & 1) << 6, nq = (wv >> 1) << 6;
  const int fm = lane & 15, fq = lane >> 4;
  floatx4 acc[4][4] = {};
  for (int k0 = 0; k0 < K; k0 += 32) {
    // global loads (before barrier)
    const __bf16* pAh = Ah + (long)(m0 + arow) * K + k0 + akq;
    const __bf16* pAl = Al + (long)(m0 + arow) * K + k0 + akq;
    bf16x8 a0 = *(const bf16x8*)pAh;
    bf16x8 a1 = *(const bf16x8*)(pAh + 8);
    bf16x8 a2 = *(const bf16x8*)pAl;
    bf16x8 a3 = *(const bf16x8*)(pAl + 8);
    const float* pB = B + (long)(k0 + bkb) * HWN + n0 + bn;
    float2 v[8];
#pragma unroll
    for (int r = 0; r < 8; ++r) v[r] = *(const float2*)(pB + (long)r * HWN);
    bf16x8 bh0, bh1, bl0, bl1;
#pragma unroll
    for (int r = 0; r < 8; ++r) {
      float vx = v[r].x, vy = v[r].y;
      __bf16 hx = (__bf16)vx, hy = (__bf16)vy;
      bh0[r] = hx;
      bh1[r] = hy;
      bl0[r] = (__bf16)(vx - (float)hx);
      bl1[r] = (__bf16)(vy - (float)hy);
    }
    __syncthreads();  // previous iter's frag reads done
    *(bf16x8*)&sAh[arow * LSTR + akq] = a0;
    *(bf16x8*)&sAh[arow * LSTR + akq + 8] = a1;
    *(bf16x8*)&sAl[arow * LSTR + akq] = a2;
    *(bf16x8*)&sAl[arow * LSTR + akq + 8] = a3;
    *(bf16x8*)&sBh[bn * LSTR + bkb] = bh0;
    *(bf16x8*)&sBh[(bn + 1) * LSTR + bkb] = bh1;
    *(bf16x8*)&sBl[bn * LSTR + bkb] = bl0;
    *(bf16x8*)&sBl[(bn + 1) * LSTR + bkb] = bl1;
    __syncthreads();
    bf16x8 fAh[4], fAl[4];
#pragma unroll
    for (int i = 0; i < 4; ++i) {
      fAh[i] = *(const bf16x8*)&sAh[(mq + i * 16 + fm) * LSTR + fq * 8];
      fAl[i] = *(const bf16x8*)&sAl[(mq + i * 16 + fm) * LSTR + fq * 8];
    }
#pragma unroll
    for (int j = 0; j < 4; ++j) {
      bf16x8 bh = *(const bf16x8*)&sBh[(nq + j * 16 + fm) * LSTR + fq * 8];
      bf16x8 bl = *(const bf16x8*)&sBl[(nq + j * 16 + fm) * LSTR + fq * 8];
#pragma unroll
      for (int i = 0; i < 4; ++i) {
        acc[i][j] = __builtin_amdgcn_mfma_f32_16x16x32_bf16(fAh[i], bh, acc[i][j], 0, 0, 0);
        acc[i][j] = __builtin_amdgcn_mfma_f32_16x16x32_bf16(fAl[i], bh, acc[i][j], 0, 0, 0);
        acc[i][j] = __builtin_amdgcn_mfma_f32_16x16x32_bf16(fAh[i], bl, acc[i][j], 0, 0, 0);
      }
    }
  }
#pragma unroll
  for (int i = 0; i < 4; ++i)
#pragma unroll
    for (int j = 0; j < 4; ++j) {
      const int col = n0 + nq + j * 16 + fm;
#pragma unroll
      for (int r = 0; r < 4; ++r) {
        const int row = m0 + mq + i * 16 + fq * 4 + r;
        C[(long)row * HWN + col] = acc[i][j][r];
      }
    }
}

// ---------- split fp32 -> bf16 hi/lo ----------
__global__ __launch_bounds__(256) void split_w(
    const float* __restrict__ w, __bf16* __restrict__ hi, __bf16* __restrict__ lo, int n) {
  int i = blockIdx.x * 256 + threadIdx.x;
  if (i < n) {
    float v = w[i];
    __bf16 h = (__bf16)v;
    hi[i] = h;
    lo[i] = (__bf16)(v - (float)h);
  }
}

// ---------- dw_all: depthwise 3x3 on ALL 1152 channels, + q/k sumsq fused ----------
__global__ __launch_bounds__(256) void dw_all(
    const float* __restrict__ qkv1, const float* __restrict__ dww,
    float* __restrict__ dwout, float* __restrict__ qs, float* __restrict__ ks, int b0) {
  __shared__ float L[10 * 128];
  const int tid = threadIdx.x;
  const int ytile = blockIdx.x;
  const int ch = blockIdx.y;
  const int bz = blockIdx.z;
  const int y0 = ytile << 3;
  const float* sp = qkv1 + ((long)bz * 1152 + ch) * HWN;
#pragma unroll
  for (int i = tid; i < 1280; i += 256) {
    int r = i >> 7, cx = i & 127;
    int gy = y0 - 1 + r;
    L[i] = (gy >= 0 && gy < WDIM) ? sp[gy * WDIM + cx] : 0.f;
  }
  const float* wp = dww + (long)ch * 9;
  float w00 = wp[0], w01 = wp[1], w02 = wp[2];
  float w10 = wp[3], w11 = wp[4], w12 = wp[5];
  float w20 = wp[6], w21 = wp[7], w22 = wp[8];
  __syncthreads();
  const int x = tid & 127;
  const int ys = (tid >> 7) << 2;
  float acc[4] = {0.f, 0.f, 0.f, 0.f};
#pragma unroll
  for (int r = 0; r < 6; ++r) {
    const float* row = L + (ys + r) * 128;
    float a = (x > 0) ? row[x - 1] : 0.f;
    float m = row[x];
    float c = (x < 127) ? row[x + 1] : 0.f;
#pragma unroll
    for (int j = 0; j < 4; ++j) {
      int wr = r - j;
      if (wr == 0) acc[j] += w00 * a + w01 * m + w02 * c;
      if (wr == 1) acc[j] += w10 * a + w11 * m + w12 * c;
      if (wr == 2) acc[j] += w20 * a + w21 * m + w22 * c;
    }
  }
  float* op = dwout + ((long)bz * 1152 + ch) * HWN + (y0 + ys) * WDIM + x;
  op[0] = acc[0];
  op[128] = acc[1];
  op[256] = acc[2];
  op[384] = acc[3];
  if (ch < 768) {
    float sq = acc[0] * acc[0] + acc[1] * acc[1] + acc[2] * acc[2] + acc[3] * acc[3];
#pragma unroll
    for (int off = 32; off >= 1; off >>= 1) sq += __shfl_down(sq, off, 64);
    if ((tid & 63) == 0) {
      int b = b0 + bz;
      if (ch < 384)
        atomicAdd(qs + b * 384 + ch, sq);
      else
        atomicAdd(ks + b * 384 + (ch - 384), sq);
    }
  }
}

// ---------- gram48: G[b,h] += Qd(48,P) * Kd(48,P)^T over a 512-px chunk ----------
__global__ __launch_bounds__(64) void gram48(
    const float* __restrict__ dwout, float* __restrict__ gram, int b0) {
  __shared__ float qt[48 * 65];
  __shared__ float kt[48 * 65];
  const int tid = threadIdx.x;
  const int kc = blockIdx.x;
  const int h = blockIdx.y;
  const int bz = blockIdx.z;
  const float* Q = dwout + ((long)bz * 1152 + h * 48) * HWN;
  const float* K = Q + 384L * HWN;
  const int c0 = (tid & 7) * 6;
  const int d0 = (tid >> 3) * 6;
  float g[6][6] = {};
  for (int p0 = kc * 512; p0 < kc * 512 + 512; p0 += 64) {
#pragma unroll 4
    for (int c = 0; c < 48; ++c) {
      qt[c * 65 + tid] = Q[(long)c * HWN + p0 + tid];
      kt[c * 65 + tid] = K[(long)c * HWN + p0 + tid];
    }
    __syncthreads();
#pragma unroll 8
    for (int p = 0; p < 64; ++p) {
      float a[6], e[6];
#pragma unroll
      for (int i = 0; i < 6; ++i) a[i] = qt[(c0 + i) * 65 + p];
#pragma unroll
      for (int j = 0; j < 6; ++j) e[j] = kt[(d0 + j) * 65 + p];
#pragma unroll
      for (int i = 0; i < 6; ++i)
#pragma unroll
        for (int j = 0; j < 6; ++j) g[i][j] += a[i] * e[j];
    }
    __syncthreads();
  }
  float* gb = gram + (long)((b0 + bz) * 8 + h) * 2304;
#pragma unroll
  for (int i = 0; i < 6; ++i)
#pragma unroll
    for (int j = 0; j < 6; ++j) atomicAdd(gb + (c0 + i) * 48 + d0 + j, g[i][j]);
}

// ---------- K3: normalize Gram, top-7, masked softmax -> attn ----------
__global__ __launch_bounds__(64) void topk_softmax(
    const float* __restrict__ gram, const float* __restrict__ qs, const float* __restrict__ ks,
    const float* __restrict__ temp, float* __restrict__ attn, int b0) {
  const int z = blockIdx.x;
  const int b = b0 + (z >> 3), h = z & 7;
  __shared__ float kn[48];
  const int tid = threadIdx.x;
  if (tid < 48) kn[tid] = fmaxf(sqrtf(ks[b * 384 + h * 48 + tid]), 1e-12f);
  __syncthreads();
  if (tid >= 48) return;
  const int c = tid;
  float qn = fmaxf(sqrtf(qs[b * 384 + h * 48 + c]), 1e-12f);
  float tv = temp[h];
  const float* gr = gram + (long)(b * 8 + h) * 2304 + c * 48;
  float s[48];
#pragma unroll
  for (int d = 0; d < 48; ++d) s[d] = gr[d] / (qn * kn[d]) * tv;
  unsigned long long sel = 0ull;
  float m0 = 0.f;
  for (int it = 0; it < 7; ++it) {
    float mx = -3.0e38f;
    int mi = 0;
#pragma unroll
    for (int d = 0; d < 48; ++d) {
      bool taken = (sel >> d) & 1ull;
      if (!taken && s[d] > mx) { mx = s[d]; mi = d; }
    }
    sel |= (1ull << mi);
    if (it == 0) m0 = mx;
  }
  float sum = 0.f;
  float e[48];
#pragma unroll
  for (int d = 0; d < 48; ++d) {
    bool t = (sel >> d) & 1ull;
    float ev = t ? expf(s[d] - m0) : 0.f;
    e[d] = ev;
    sum += ev;
  }
  float inv = 1.f / sum;
  float* ar = attn + (long)(b * 8 + h) * 2304 + c * 48;
#pragma unroll
  for (int d = 0; d < 48; ++d) ar[d] = e[d] * inv;
}

// ---------- K4: M_b = proj_w @ blockdiag(attn_b) -> split bf16 hi/lo ----------
__global__ __launch_bounds__(256) void build_M(
    const float* __restrict__ attn, const float* __restrict__ pw,
    __bf16* __restrict__ Mh, __bf16* __restrict__ Ml, int b0) {
  const int b = b0 + blockIdx.x;
  const int h = blockIdx.y;
  __shared__ float at[48][49];
  const int tid = threadIdx.x;
  for (int i = tid; i < 2304; i += 256) at[i / 48][i % 48] = attn[(long)(b * 8 + h) * 2304 + i];
  __syncthreads();
  for (int idx = tid; idx < 384 * 48; idx += 256) {
    int o = idx / 48, d = idx % 48;
    const float* pr = pw + (long)o * 384 + h * 48;
    float acc = 0.f;
#pragma unroll
    for (int c = 0; c < 48; ++c) acc += pr[c] * at[c][d];
    long oi = ((long)b * 384 + o) * 384 + h * 48 + d;
    __bf16 hh = (__bf16)acc;
    Mh[oi] = hh;
    Ml[oi] = (__bf16)(acc - (float)hh);
  }
}

extern "C" void kernel_launch(void* const* d_in, const int* in_sizes, int n_in,
                              void* d_out, int out_size, void* d_ws, size_t ws_size,
                              hipStream_t stream) {
  const float* x = (const float*)d_in[0];       // (8,384,128,128)
  const float* qkv_w = (const float*)d_in[1];   // (1152,384)
  const float* dw_w = (const float*)d_in[2];    // (1152,1,3,3)
  const float* proj_w = (const float*)d_in[3];  // (384,384)
  const float* temp = (const float*)d_in[4];    // (8,)
  float* out = (float*)d_out;
  float* ws = (float*)d_ws;

  // ws layout
  float* gram = ws;                          // 147456 f
  float* qs = gram + 147456;                 // 3072 f
  float* ks = qs + 3072;                     // 3072 f
  float* attn = ks + 3072;                   // 147456 f
  __bf16* Wh = (__bf16*)(attn + 147456);     // 442368 bf16
  __bf16* Wl = Wh + 442368;                  // 442368 bf16
  __bf16* Mh = Wl + 442368;                  // 8*147456 bf16
  __bf16* Ml = Mh + 1179648;                 // 8*147456 bf16
  float* qkv1 = (float*)(Ml + 1179648);      // nb*1152*16384 f
  const long SMALLS = 1333248L;              // floats
  const long PERB = 37748736L;               // qkv1 + dwout per batch (floats)
  long wsf = (long)(ws_size / 4);
  int nb = (int)((wsf - SMALLS) / PERB);
  if (nb < 1) nb = 1;
  if (nb > 8) nb = 8;
  float* dwout = qkv1 + (long)nb * 18874368L;

  hipMemsetAsync(gram, 0, (147456 + 3072 + 3072) * sizeof(float), stream);
  split_w<<<dim3((442368 + 255) / 256), 256, 0, stream>>>(qkv_w, Wh, Wl, 442368);

  for (int b0 = 0; b0 < 8; b0 += nb) {
    int nbc = (8 - b0 < nb) ? (8 - b0) : nb;
    // K1: qkv1 = W @ x[b]   (M=1152, K=384), split-bf16 MFMA
    gemm_mfma3<<<dim3(128, 9, nbc), 256, 0, stream>>>(
        Wh, Wl, x + (long)b0 * 6291456L, qkv1, 384, 0L, 6291456L, 18874368L);
    // dw: all 1152 channels, q/k sumsq fused
    dw_all<<<dim3(16, 1152, nbc), 256, 0, stream>>>(qkv1, dw_w, dwout, qs, ks, b0);
    // gram
    gram48<<<dim3(32, 8, nbc), 64, 0, stream>>>(dwout, gram, b0);
    // attn
    topk_softmax<<<dim3(nbc * 8), 64, 0, stream>>>(gram, qs, ks, temp, attn, b0);
    // M_b (split bf16)
    build_M<<<dim3(nbc, 8), 256, 0, stream>>>(attn, proj_w, Mh, Ml, b0);
    // K5: out[b] = M_b @ v[b]   (M=384, K=384), split-bf16 MFMA
    gemm_mfma3<<<dim3(128, 3, nbc), 256, 0, stream>>>(
        Mh + (long)b0 * 147456L, Ml + (long)b0 * 147456L, dwout + 768L * HWN,
        out + (long)b0 * 6291456L, 384, 147456L, 18874368L, 6291456L);
  }
}